// Round 3
// baseline (776.835 us; speedup 1.0000x reference)
//
#include <hip/hip_runtime.h>
#include <math.h>

// GCN forward: out = sigmoid( relu(A @ (relu(A @ (X@W1) + b1) @ W2) + b2) @ Wf + bf )
// N=8192, F_IN=256, H=128, all f32 inputs/outputs.
//
// Strategy: the two A@Z products (17.2 GF each) use bf16x3 split-MFMA
// (Ah@Zh + Ah@Zl + Al@Zh, RNE hi + exact-residual lo => ~17 mantissa bits).
// A is split on the fly in registers (no LDS at all in the big kernel);
// Z is precomputed split + transposed ([col][k]) so B-fragments are
// 16B-contiguous per lane and L2-resident (4 MB).
// k_agg is HBM-bound on streaming A (256 MB -> ~41 us floor); the 3x MFMA
// and the in-register split are hidden under the A-stream.

typedef float   f32x4   __attribute__((ext_vector_type(4)));
typedef float   float4v __attribute__((ext_vector_type(4)));
typedef short   bf16x8  __attribute__((ext_vector_type(8)));
typedef unsigned short ushort4v __attribute__((ext_vector_type(4)));

#define N_NODES 8192
#define HDIM    128

// f32 -> (bf16 hi RNE, bf16 lo RNE of exact residual)
__device__ __forceinline__ void split2(float a, unsigned short& h, unsigned short& l) {
  unsigned int u = __float_as_uint(a);
  unsigned int r = u + 0x7FFFu + ((u >> 16) & 1u);
  h = (unsigned short)(r >> 16);
  float hf = __uint_as_float((r >> 16) << 16);
  float lo = a - hf;                      // exact residual
  unsigned int ul = __float_as_uint(lo);
  unsigned int rl = ul + 0x7FFFu + ((ul >> 16) & 1u);
  l = (unsigned short)(rl >> 16);
}

// Z^T split producer: Zh/Zl[c][r] = split(sum_k X[r][k]*W[k][c]), c<128.
// Block: 256 threads -> tile of 32 rows x 32 cols. grid = (8192/32)*(128/32) = 1024.
template <int K>
__global__ __launch_bounds__(256) void k_inproj(const float* __restrict__ X,
                                                const float* __restrict__ W,
                                                unsigned short* __restrict__ Zh,
                                                unsigned short* __restrict__ Zl) {
  __shared__ float xs[32 * K];
  int bid = blockIdx.x;
  int rb = bid >> 2, cb = bid & 3;
  int r0 = rb * 32, c0 = cb * 32;
  const float* src = X + (size_t)r0 * K;       // 32 rows are contiguous
  for (int i = threadIdx.x; i < 32 * K / 4; i += 256)
    ((float4v*)xs)[i] = ((const float4v*)src)[i];
  __syncthreads();

  int c = threadIdx.x & 31, rg = threadIdx.x >> 5;   // rg in [0,8): 4 rows each
  float acc[4] = {0.f, 0.f, 0.f, 0.f};
  for (int k = 0; k < K; ++k) {
    float w = W[k * HDIM + c0 + c];
#pragma unroll
    for (int i = 0; i < 4; ++i) acc[i] += xs[(rg * 4 + i) * K + k] * w;
  }
  ushort4v hv, lv;
#pragma unroll
  for (int i = 0; i < 4; ++i) { unsigned short h, l; split2(acc[i], h, l); hv[i] = h; lv[i] = l; }
  size_t o = (size_t)(c0 + c) * N_NODES + (size_t)r0 + rg * 4;
  *(ushort4v*)(Zh + o) = hv;
  *(ushort4v*)(Zl + o) = lv;
}

// Big kernel: partial[q] = A[:, q*2048:(q+1)*2048] @ Z[q-range, :]
// 256 blocks x 256 thr. Block = 128 rows x one K-quarter; wave = 32 rows x 128 cols.
// No LDS: A frags loaded f32 from HBM + split in regs; B frags from L2 (Z^T split).
__global__ __launch_bounds__(256) void k_agg(const float* __restrict__ A,
                                             const unsigned short* __restrict__ Zh,
                                             const unsigned short* __restrict__ Zl,
                                             float* __restrict__ pbuf) {
  const int N = N_NODES;
  int bid = blockIdx.x;
  int q = bid & 3, rbk = bid >> 2;
  int w = threadIdx.x >> 6, lane = threadIdx.x & 63;
  int lr = lane & 15, lg = lane >> 4;
  int wr0 = rbk * 128 + w * 32;
  int k0 = q * 2048;

  const float* ar0 = A + (size_t)(wr0 + lr) * N;
  const float* ar1 = A + (size_t)(wr0 + 16 + lr) * N;

  f32x4 acc[2][8] = {};

  int kk = k0 + lg * 8;
  float4v a0n = *(const float4v*)(ar0 + kk);
  float4v a1n = *(const float4v*)(ar0 + kk + 4);
  float4v a2n = *(const float4v*)(ar1 + kk);
  float4v a3n = *(const float4v*)(ar1 + kk + 4);

  for (int ks = 0; ks < 64; ++ks) {
    float4v a0 = a0n, a1 = a1n, a2 = a2n, a3 = a3n;
    if (ks < 63) {                      // prefetch next A (covers HBM latency)
      int kn = kk + 32;
      a0n = *(const float4v*)(ar0 + kn);
      a1n = *(const float4v*)(ar0 + kn + 4);
      a2n = *(const float4v*)(ar1 + kn);
      a3n = *(const float4v*)(ar1 + kn + 4);
    }
    // B fragment loads (L2-resident): lane reads 8 contiguous bf16 at [col][kk]
    bf16x8 bh[8], bl[8];
#pragma unroll
    for (int cg = 0; cg < 8; ++cg) {
      size_t zo = (size_t)(cg * 16 + lr) * N + kk;
      bh[cg] = *(const bf16x8*)(Zh + zo);
      bl[cg] = *(const bf16x8*)(Zl + zo);
    }
    // split current A into hi/lo fragments (VALU, hidden under MFMA+VMEM)
    bf16x8 ah[2], al[2];
#pragma unroll
    for (int i = 0; i < 4; ++i) {
      unsigned short h, l;
      split2(a0[i], h, l); ah[0][i]     = (short)h; al[0][i]     = (short)l;
      split2(a1[i], h, l); ah[0][4 + i] = (short)h; al[0][4 + i] = (short)l;
      split2(a2[i], h, l); ah[1][i]     = (short)h; al[1][i]     = (short)l;
      split2(a3[i], h, l); ah[1][4 + i] = (short)h; al[1][4 + i] = (short)l;
    }
    // 48 MFMAs: 2 row-frags x 8 col-frags x 3 products, all into same acc
#pragma unroll
    for (int rg = 0; rg < 2; ++rg)
#pragma unroll
      for (int cg = 0; cg < 8; ++cg) {
        acc[rg][cg] = __builtin_amdgcn_mfma_f32_16x16x32_bf16(ah[rg], bh[cg], acc[rg][cg], 0, 0, 0);
        acc[rg][cg] = __builtin_amdgcn_mfma_f32_16x16x32_bf16(ah[rg], bl[cg], acc[rg][cg], 0, 0, 0);
        acc[rg][cg] = __builtin_amdgcn_mfma_f32_16x16x32_bf16(al[rg], bh[cg], acc[rg][cg], 0, 0, 0);
      }
    kk += 32;
  }
  // C/D layout (m89-verified): col = lane&15, row = (lane>>4)*4 + j
  float* pq = pbuf + (size_t)q * N_NODES * HDIM;
#pragma unroll
  for (int rg = 0; rg < 2; ++rg)
#pragma unroll
    for (int cg = 0; cg < 8; ++cg) {
      int col  = cg * 16 + lr;
      int rowb = wr0 + rg * 16 + lg * 4;
#pragma unroll
      for (int j = 0; j < 4; ++j)
        pq[(size_t)(rowb + j) * HDIM + col] = acc[rg][cg][j];
    }
}

// partial reduce + bias + relu
__global__ __launch_bounds__(256) void k_reduce(const float* __restrict__ pbuf,
                                                const float* __restrict__ bias,
                                                float* __restrict__ h) {
  int i = blockIdx.x * 256 + threadIdx.x;
  const int M = N_NODES * HDIM;
  float s = pbuf[i] + pbuf[i + M] + pbuf[i + 2 * M] + pbuf[i + 3 * M] + bias[i & (HDIM - 1)];
  h[i] = fmaxf(s, 0.f);
}

// out[row] = sigmoid(h[row,:] . Wf + bf); one wave per row
__global__ __launch_bounds__(256) void k_final(const float* __restrict__ h,
                                               const float* __restrict__ Wf,
                                               const float* __restrict__ bf,
                                               float* __restrict__ out) {
  int wv = threadIdx.x >> 6, lane = threadIdx.x & 63;
  int row = blockIdx.x * 4 + wv;
  const float* hr = h + (size_t)row * HDIM;
  float s = hr[lane] * Wf[lane] + hr[lane + 64] * Wf[lane + 64];
#pragma unroll
  for (int m = 32; m >= 1; m >>= 1) s += __shfl_xor(s, m, 64);
  if (lane == 0) out[row] = 1.f / (1.f + expf(-(s + bf[0])));
}

extern "C" void kernel_launch(void* const* d_in, const int* in_sizes, int n_in,
                              void* d_out, int out_size, void* d_ws, size_t ws_size,
                              hipStream_t stream) {
  const float* X  = (const float*)d_in[0];
  const float* A  = (const float*)d_in[1];
  const float* W1 = (const float*)d_in[2];
  const float* b1 = (const float*)d_in[3];
  const float* W2 = (const float*)d_in[4];
  const float* b2 = (const float*)d_in[5];
  const float* Wf = (const float*)d_in[6];
  const float* bf = (const float*)d_in[7];
  float* out = (float*)d_out;

  char* ws = (char*)d_ws;
  unsigned short* Zh = (unsigned short*)ws;               //  2 MB
  unsigned short* Zl = (unsigned short*)(ws + (2u << 20)); //  2 MB
  float* pbuf = (float*)(ws + (4u << 20));                // 16 MB
  float* h    = (float*)(ws + (20u << 20));               //  4 MB

  // layer 1
  k_inproj<256><<<1024, 256, 0, stream>>>(X, W1, Zh, Zl);
  k_agg<<<256, 256, 0, stream>>>(A, Zh, Zl, pbuf);
  k_reduce<<<4096, 256, 0, stream>>>(pbuf, b1, h);
  // layer 2
  k_inproj<128><<<1024, 256, 0, stream>>>(h, W2, Zh, Zl);
  k_agg<<<256, 256, 0, stream>>>(A, Zh, Zl, pbuf);
  k_reduce<<<4096, 256, 0, stream>>>(pbuf, b2, h);
  // head
  k_final<<<2048, 256, 0, stream>>>(h, Wf, bf, out);
}